// Round 7
// baseline (432.297 us; speedup 1.0000x reference)
//
#include <hip/hip_runtime.h>
#include <hip/hip_bf16.h>
#include <hip/hip_fp16.h>
#include <math.h>

#define NEG_SLOPE 0.2f

typedef _Float16 f16x8 __attribute__((ext_vector_type(8)));
typedef float f32x4  __attribute__((ext_vector_type(4)));
typedef _Float16 h2v __attribute__((ext_vector_type(2)));

union U2 { uint2 u; h2v h[2]; };

__device__ __forceinline__ h2v pk_lrelu(h2v s){
    h2v k = { (_Float16)NEG_SLOPE, (_Float16)NEG_SLOPE };
    return __builtin_elementwise_max(s, s * k);
}

__device__ __forceinline__ float dot4_lrelu(h2v v01, h2v v23, h2v x01, h2v x23,
                                            h2v a01, h2v a23){
    h2v t01 = pk_lrelu(v01 + x01);
    h2v t23 = pk_lrelu(v23 + x23);
#if __has_builtin(__builtin_amdgcn_fdot2)
    return __builtin_amdgcn_fdot2(t01, a01,
           __builtin_amdgcn_fdot2(t23, a23, 0.f, false), false);
#else
    return (float)t01[0]*(float)a01[0] + (float)t01[1]*(float)a01[1]
         + (float)t23[0]*(float)a23[0] + (float)t23[1]*(float)a23[1];
#endif
}

// ---------------- CSR build ----------------

__global__ void zero_int(int* __restrict__ p, int n){
    int i = blockIdx.x*256 + threadIdx.x;
    if (i < n) p[i] = 0;
}

__global__ void hist_k(const int* __restrict__ dst, int E, int* __restrict__ cnt){
    int e = blockIdx.x*256 + threadIdx.x;
    if (e < E) atomicAdd(&cnt[dst[e]], 1);
}

__global__ void scan1_k(const int* __restrict__ deg, int Nn, int* __restrict__ rp, int* __restrict__ bsum){
    __shared__ int s[256];
    int t = threadIdx.x, b = blockIdx.x;
    int i = b*256 + t;
    int v = (i < Nn) ? deg[i] : 0;
    s[t] = v;
    __syncthreads();
    #pragma unroll
    for (int d = 1; d < 256; d <<= 1){
        int u = (t >= d) ? s[t-d] : 0;
        __syncthreads();
        s[t] += u;
        __syncthreads();
    }
    if (i < Nn) rp[i] = s[t] - v;
    if (t == 255) bsum[b] = s[255];
}

__global__ void scan2_k(const int* __restrict__ bsum, int nb, int* __restrict__ bsumx){
    __shared__ int s[256];
    int t = threadIdx.x;
    int v = (t < nb) ? bsum[t] : 0;
    s[t] = v;
    __syncthreads();
    #pragma unroll
    for (int d = 1; d < 256; d <<= 1){
        int u = (t >= d) ? s[t-d] : 0;
        __syncthreads();
        s[t] += u;
        __syncthreads();
    }
    if (t < nb) bsumx[t] = s[t] - v;
}

__global__ void scan3_k(int* __restrict__ rp, const int* __restrict__ bsumx,
                        int* __restrict__ cnt, int Nn, int E){
    int b = blockIdx.x, t = threadIdx.x;
    int i = b*256 + t;
    if (i < Nn){
        int r = rp[i] + bsumx[b];
        rp[i]  = r;
        cnt[i] = r;
    }
    if (b == 0 && t == 0) rp[Nn] = E;
}

// items[rp[i]+i] = i (self-loop slot); idst likewise
__global__ void self_k(const int* __restrict__ rp, int* __restrict__ items,
                       int* __restrict__ idst, int Nn){
    int i = blockIdx.x*256 + threadIdx.x;
    if (i < Nn){ int p = rp[i] + i; items[p] = i; idst[p] = i; }
}

__global__ void scatter_k(const int* __restrict__ src, const int* __restrict__ dst,
                          int E, int* __restrict__ cnt,
                          int* __restrict__ items, int* __restrict__ idst){
    int e = blockIdx.x*256 + threadIdx.x;
    if (e < E){
        int d = dst[e];
        int pos = atomicAdd(&cnt[d], 1);
        items[pos + d + 1] = src[e];
        idst [pos + d + 1] = d;
    }
}

// ---------------- conversions ----------------

__global__ void cvt_x_k(const float* __restrict__ X, _Float16* __restrict__ O, int n4){
    int i = blockIdx.x*256 + threadIdx.x;
    if (i >= n4) return;
    float4 v = reinterpret_cast<const float4*>(X)[i];
    U2 o;
    o.h[0][0] = (_Float16)v.x; o.h[0][1] = (_Float16)v.y;
    o.h[1][0] = (_Float16)v.z; o.h[1][1] = (_Float16)v.w;
    reinterpret_cast<uint2*>(O)[i] = o.u;
}

// weights [K][Nw] (two of them) -> transposed Bt[2*Nw][K] fp16
__global__ void cvt_w_k(const float* __restrict__ Wl, const float* __restrict__ Wr,
                        int Nw, int K, _Float16* __restrict__ Bt){
    int t = blockIdx.x*256 + threadIdx.x;
    int total = 2*Nw*K;
    if (t >= total) return;
    int k = t & (K-1);
    int n = t >> 8;                 // K == 256
    float v = (n < Nw) ? Wl[(size_t)k*Nw + n] : Wr[(size_t)k*Nw + (n - Nw)];
    Bt[t] = (_Float16)v;
}

__global__ void cvt_att_k(const float* __restrict__ a1, const float* __restrict__ a2,
                          _Float16* __restrict__ o1, _Float16* __restrict__ o2){
    int t = threadIdx.x;
    o1[t] = (_Float16)a1[t];
    if (t < 64) o2[t] = (_Float16)a2[t];
}

// ---------------- fp16 MFMA GEMM: C = A @ B, B given as Bt[Ntot][K], all fp16 ----------------
__global__ __launch_bounds__(256) void gemm_f16(
    const _Float16* __restrict__ A, const _Float16* __restrict__ Bt,
    _Float16* __restrict__ C, int M, int Ntot, int K)
{
    __shared__ __align__(16) _Float16 sA[128*40];
    __shared__ __align__(16) _Float16 sB[128*40];

    int t = threadIdx.x;
    int lane = t & 63, wave = t >> 6;
    int wm = (wave >> 1) * 64, wn = (wave & 1) * 64;
    int m0 = blockIdx.y * 128, n0 = blockIdx.x * 128;
    int lm = lane & 15, kq = lane >> 4;

    f32x4 acc[4][4] = {};

    for (int kc = 0; kc < K; kc += 32){
        __syncthreads();
        #pragma unroll
        for (int it = 0; it < 2; ++it){
            int idx = t + 256*it;
            int r = idx >> 2, s = (idx & 3) * 8;
            uint4 va = make_uint4(0u,0u,0u,0u);
            if (m0 + r < M)
                va = *reinterpret_cast<const uint4*>(A + (size_t)(m0 + r)*K + kc + s);
            *reinterpret_cast<uint4*>(sA + r*40 + s) = va;
            *reinterpret_cast<uint4*>(sB + r*40 + s) =
                *reinterpret_cast<const uint4*>(Bt + (size_t)(n0 + r)*K + kc + s);
        }
        __syncthreads();

        f16x8 fa[4], fb[4];
        #pragma unroll
        for (int i = 0; i < 4; ++i){
            fa[i] = *reinterpret_cast<const f16x8*>(sA + (wm + i*16 + lm)*40 + kq*8);
            fb[i] = *reinterpret_cast<const f16x8*>(sB + (wn + i*16 + lm)*40 + kq*8);
        }
        #pragma unroll
        for (int i = 0; i < 4; ++i)
            #pragma unroll
            for (int j = 0; j < 4; ++j)
                acc[i][j] = __builtin_amdgcn_mfma_f32_16x16x32_f16(fa[i], fb[j], acc[i][j], 0, 0, 0);
    }

    #pragma unroll
    for (int i = 0; i < 4; ++i){
        #pragma unroll
        for (int r = 0; r < 4; ++r){
            int m = m0 + wm + i*16 + kq*4 + r;
            if (m < M){
                #pragma unroll
                for (int j = 0; j < 4; ++j)
                    C[(size_t)m*Ntot + n0 + wn + j*16 + lm] = (_Float16)acc[i][j][r];
            }
        }
    }
}

// ---------------- layer-1 aggregation: wave per node, ILP-4 + 8-deep prefetch ----------------
// xlr [N][512] fp16: cols 0..255 = xl, 256..511 = xr. items = self+edges CSR.
__global__ __launch_bounds__(256) void agg1_k(
    const _Float16* __restrict__ xlr,
    const int* __restrict__ rp, const int* __restrict__ items,
    const _Float16* __restrict__ attH, const float* __restrict__ bias,
    _Float16* __restrict__ h1, int Nn)
{
    int wave = threadIdx.x >> 6, lane = threadIdx.x & 63;
    int i = blockIdx.x*4 + wave;
    if (i >= Nn) return;
    int off = lane*4;
    U2 xr; xr.u = *reinterpret_cast<const uint2*>(xlr + (size_t)i*512 + 256 + off);
    U2 at; at.u = *reinterpret_cast<const uint2*>(attH + off);
    int beg = rp[i] + i;
    int n   = rp[i+1] + 1 - rp[i];        // items count (>=1)

    auto rowld = [&](int j)->uint2 {
        int jj = (j < n) ? j : (n-1);
        int sn = items[beg + jj];
        return *reinterpret_cast<const uint2*>(xlr + (size_t)sn*512 + off);
    };

    float l = 0.f;
    float4 acc = make_float4(0.f,0.f,0.f,0.f);

    uint2 r0=rowld(0), r1=rowld(1), r2=rowld(2), r3=rowld(3);
    uint2 r4=rowld(4), r5=rowld(5), r6=rowld(6), r7=rowld(7);
    for (int j = 0; j < n; j += 4){
        uint2 p0=rowld(j+8), p1=rowld(j+9), p2=rowld(j+10), p3=rowld(j+11);
        U2 c0,c1,c2,c3; c0.u=r0; c1.u=r1; c2.u=r2; c3.u=r3;
        float s0 = dot4_lrelu(c0.h[0], c0.h[1], xr.h[0], xr.h[1], at.h[0], at.h[1]);
        float s1 = dot4_lrelu(c1.h[0], c1.h[1], xr.h[0], xr.h[1], at.h[0], at.h[1]);
        float s2 = dot4_lrelu(c2.h[0], c2.h[1], xr.h[0], xr.h[1], at.h[0], at.h[1]);
        float s3 = dot4_lrelu(c3.h[0], c3.h[1], xr.h[0], xr.h[1], at.h[0], at.h[1]);
        s0 += __shfl_xor(s0, 8, 64); s1 += __shfl_xor(s1, 8, 64);
        s2 += __shfl_xor(s2, 8, 64); s3 += __shfl_xor(s3, 8, 64);
        s0 += __shfl_xor(s0, 4, 64); s1 += __shfl_xor(s1, 4, 64);
        s2 += __shfl_xor(s2, 4, 64); s3 += __shfl_xor(s3, 4, 64);
        s0 += __shfl_xor(s0, 2, 64); s1 += __shfl_xor(s1, 2, 64);
        s2 += __shfl_xor(s2, 2, 64); s3 += __shfl_xor(s3, 2, 64);
        s0 += __shfl_xor(s0, 1, 64); s1 += __shfl_xor(s1, 1, 64);
        s2 += __shfl_xor(s2, 1, 64); s3 += __shfl_xor(s3, 1, 64);
        float w0 = __expf(s0);
        float w1 = (j+1 < n) ? __expf(s1) : 0.f;
        float w2 = (j+2 < n) ? __expf(s2) : 0.f;
        float w3 = (j+3 < n) ? __expf(s3) : 0.f;
        l += (w0 + w1) + (w2 + w3);
        acc.x += (w0*(float)c0.h[0][0] + w1*(float)c1.h[0][0])
               + (w2*(float)c2.h[0][0] + w3*(float)c3.h[0][0]);
        acc.y += (w0*(float)c0.h[0][1] + w1*(float)c1.h[0][1])
               + (w2*(float)c2.h[0][1] + w3*(float)c3.h[0][1]);
        acc.z += (w0*(float)c0.h[1][0] + w1*(float)c1.h[1][0])
               + (w2*(float)c2.h[1][0] + w3*(float)c3.h[1][0]);
        acc.w += (w0*(float)c0.h[1][1] + w1*(float)c1.h[1][1])
               + (w2*(float)c2.h[1][1] + w3*(float)c3.h[1][1]);
        r0=r4; r1=r5; r2=r6; r3=r7; r4=p0; r5=p1; r6=p2; r7=p3;
    }

    float inv = 1.f / l;
    float4 b4 = *reinterpret_cast<const float4*>(&bias[off]);
    U2 o;
    o.h[0][0] = (_Float16)fmaxf(acc.x*inv + b4.x, 0.f);
    o.h[0][1] = (_Float16)fmaxf(acc.y*inv + b4.y, 0.f);
    o.h[1][0] = (_Float16)fmaxf(acc.z*inv + b4.z, 0.f);
    o.h[1][1] = (_Float16)fmaxf(acc.w*inv + b4.w, 0.f);
    *reinterpret_cast<uint2*>(h1 + (size_t)i*256 + off) = o.u;
}

// ---------------- layer-2 phase 1: item-parallel scores ----------------
// one 16-lane quarter per item; xlr [N][128] fp16 (xl | xr)
__global__ __launch_bounds__(256) void score2_k(
    const _Float16* __restrict__ xlr,
    const int* __restrict__ items, const int* __restrict__ idst,
    const _Float16* __restrict__ attH,
    float* __restrict__ w, int nI)
{
    int t = threadIdx.x;
    int r = t & 15;
    int idx = blockIdx.x*16 + (t >> 4);
    if (idx >= nI) return;
    int s = items[idx], d = idst[idx];
    int off = r*4;
    U2 vl; vl.u = *reinterpret_cast<const uint2*>(xlr + (size_t)s*128 + off);
    U2 xr; xr.u = *reinterpret_cast<const uint2*>(xlr + (size_t)d*128 + 64 + off);
    U2 at; at.u = *reinterpret_cast<const uint2*>(attH + off);
    float sc = dot4_lrelu(vl.h[0], vl.h[1], xr.h[0], xr.h[1], at.h[0], at.h[1]);
    sc += __shfl_xor(sc, 8, 64);
    sc += __shfl_xor(sc, 4, 64);
    sc += __shfl_xor(sc, 2, 64);
    sc += __shfl_xor(sc, 1, 64);
    if (r == 0) w[idx] = __expf(sc);
}

// ---------------- layer-2 phase 2: node-parallel weighted gather + final linear ----------------
// lane = channel (64); shuffle-free loop, ILP-4, 8-deep prefetch.
__global__ __launch_bounds__(256) void gather2_k(
    const _Float16* __restrict__ xlr,
    const int* __restrict__ rp, const int* __restrict__ items,
    const float* __restrict__ w, const float* __restrict__ bias,
    const float* __restrict__ Wlin, const float* __restrict__ blin,
    float* __restrict__ out, int Nn)
{
    int wave = threadIdx.x >> 6, lane = threadIdx.x & 63;
    int i = blockIdx.x*4 + wave;
    if (i >= Nn) return;
    int beg = rp[i] + i;
    int n   = rp[i+1] + 1 - rp[i];
    const float* wp = w + beg;

    auto rowld = [&](int j)->_Float16 {
        int jj = (j < n) ? j : (n-1);
        int sn = items[beg + jj];
        return xlr[(size_t)sn*128 + lane];
    };

    float l = 0.f, acc = 0.f;
    _Float16 r0=rowld(0), r1=rowld(1), r2=rowld(2), r3=rowld(3);
    _Float16 r4=rowld(4), r5=rowld(5), r6=rowld(6), r7=rowld(7);
    for (int j = 0; j < n; j += 4){
        _Float16 p0=rowld(j+8), p1=rowld(j+9), p2=rowld(j+10), p3=rowld(j+11);
        float w0 = wp[j];
        float w1 = (j+1 < n) ? wp[j+1] : 0.f;
        float w2 = (j+2 < n) ? wp[j+2] : 0.f;
        float w3 = (j+3 < n) ? wp[j+3] : 0.f;
        l   += (w0 + w1) + (w2 + w3);
        acc += (w0*(float)r0 + w1*(float)r1) + (w2*(float)r2 + w3*(float)r3);
        r0=r4; r1=r5; r2=r6; r3=r7; r4=p0; r5=p1; r6=p2; r7=p3;
    }

    float hc = fmaxf(acc / l + bias[lane], 0.f);
    #pragma unroll
    for (int c = 0; c < 10; ++c){
        float p = hc * Wlin[lane*10 + c];
        p += __shfl_xor(p, 32, 64);
        p += __shfl_xor(p, 16, 64);
        p += __shfl_xor(p, 8, 64);
        p += __shfl_xor(p, 4, 64);
        p += __shfl_xor(p, 2, 64);
        p += __shfl_xor(p, 1, 64);
        if (lane == 0) out[(size_t)i*10 + c] = p + blin[c];
    }
}

// ---------------- launch ----------------

extern "C" void kernel_launch(void* const* d_in, const int* in_sizes, int n_in,
                              void* d_out, int out_size, void* d_ws, size_t ws_size,
                              hipStream_t stream)
{
    const float* x    = (const float*)d_in[0];
    const int*   ei   = (const int*)  d_in[1];
    const float* Wl1  = (const float*)d_in[2];
    const float* Wr1  = (const float*)d_in[3];
    const float* att1 = (const float*)d_in[4];
    const float* b1   = (const float*)d_in[5];
    const float* Wl2  = (const float*)d_in[6];
    const float* Wr2  = (const float*)d_in[7];
    const float* att2 = (const float*)d_in[8];
    const float* b2   = (const float*)d_in[9];
    const float* Wlin = (const float*)d_in[10];
    const float* blin = (const float*)d_in[11];
    float* out = (float*)d_out;

    const int N = in_sizes[0] / 256;
    const int E = in_sizes[1] / 2;
    const int K = 256;
    const int nI = E + N;
    const int* srcp = ei;
    const int* dstp = ei + E;

    char* ws = (char*)d_ws;
    size_t off = 0;
    auto alloc = [&](size_t bytes)->char*{
        char* p = ws + off;
        off += (bytes + 255) & ~(size_t)255;
        return p;
    };
    _Float16* xlr1 = (_Float16*)alloc((size_t)N*512*2);   // layer-1 xl|xr fp16
    _Float16* xlr2 = (_Float16*)alloc((size_t)N*128*2);   // layer-2 xl|xr fp16
    _Float16* xA   = (_Float16*)alloc((size_t)N*256*2);   // x fp16
    _Float16* h1   = (_Float16*)alloc((size_t)N*256*2);   // h1 fp16
    _Float16* bt1  = (_Float16*)alloc((size_t)512*K*2);
    _Float16* bt2  = (_Float16*)alloc((size_t)128*K*2);
    _Float16* a1h  = (_Float16*)alloc(256*2);
    _Float16* a2h  = (_Float16*)alloc(64*2);
    float* w2      = (float*)alloc((size_t)nI*4);
    int* rp    = (int*)alloc((size_t)(N+1)*4);
    int* cnt   = (int*)alloc((size_t)N*4);
    int* bsum  = (int*)alloc(256*4);
    int* bsumx = (int*)alloc(256*4);
    int* items = (int*)alloc((size_t)nI*4);
    int* idst  = (int*)alloc((size_t)nI*4);
    (void)ws_size;

    const int nb = (N + 255) / 256;
    const int eb = (E + 255) / 256;

    // CSR build (items = self + edges per node)
    hipLaunchKernelGGL(zero_int,  dim3(nb), dim3(256), 0, stream, cnt, N);
    hipLaunchKernelGGL(hist_k,    dim3(eb), dim3(256), 0, stream, dstp, E, cnt);
    hipLaunchKernelGGL(scan1_k,   dim3(nb), dim3(256), 0, stream, cnt, N, rp, bsum);
    hipLaunchKernelGGL(scan2_k,   dim3(1),  dim3(256), 0, stream, bsum, nb, bsumx);
    hipLaunchKernelGGL(scan3_k,   dim3(nb), dim3(256), 0, stream, rp, bsumx, cnt, N, E);
    hipLaunchKernelGGL(self_k,    dim3(nb), dim3(256), 0, stream, rp, items, idst, N);
    hipLaunchKernelGGL(scatter_k, dim3(eb), dim3(256), 0, stream, srcp, dstp, E, cnt, items, idst);

    // conversions
    hipLaunchKernelGGL(cvt_x_k, dim3((N*256/4 + 255)/256), dim3(256), 0, stream,
                       x, xA, N*256/4);
    hipLaunchKernelGGL(cvt_w_k, dim3((512*K + 255)/256), dim3(256), 0, stream,
                       Wl1, Wr1, 256, K, bt1);
    hipLaunchKernelGGL(cvt_w_k, dim3((128*K + 255)/256), dim3(256), 0, stream,
                       Wl2, Wr2, 64, K, bt2);
    hipLaunchKernelGGL(cvt_att_k, dim3(1), dim3(256), 0, stream, att1, att2, a1h, a2h);

    // layer 1
    hipLaunchKernelGGL(gemm_f16, dim3(4, (N+127)/128), dim3(256), 0, stream,
                       xA, bt1, xlr1, N, 512, K);
    hipLaunchKernelGGL(agg1_k, dim3((N+3)/4), dim3(256), 0, stream,
                       xlr1, rp, items, a1h, b1, h1, N);

    // layer 2
    hipLaunchKernelGGL(gemm_f16, dim3(1, (N+127)/128), dim3(256), 0, stream,
                       h1, bt2, xlr2, N, 128, K);
    hipLaunchKernelGGL(score2_k, dim3((nI+15)/16), dim3(256), 0, stream,
                       xlr2, items, idst, a2h, w2, nI);
    hipLaunchKernelGGL(gather2_k, dim3((N+3)/4), dim3(256), 0, stream,
                       xlr2, rp, items, w2, b2, Wlin, blin, out, N);
}

// Round 8
// 402.992 us; speedup vs baseline: 1.0727x; 1.0727x over previous
//
#include <hip/hip_runtime.h>
#include <hip/hip_fp16.h>
#include <math.h>

#define NEG_SLOPE 0.2f

typedef _Float16 f16x8 __attribute__((ext_vector_type(8)));
typedef float f32x4  __attribute__((ext_vector_type(4)));
typedef _Float16 h2v __attribute__((ext_vector_type(2)));

union U8 { uint4 u; f16x8 v; h2v h[4]; };
union U2 { uint2 u; h2v h[2]; };

__device__ __forceinline__ f16x8 lrelu8(f16x8 s){
    return __builtin_elementwise_max(s, s * (_Float16)NEG_SLOPE);
}
__device__ __forceinline__ h2v lrelu2(h2v s){
    return __builtin_elementwise_max(s, s * (_Float16)NEG_SLOPE);
}
__device__ __forceinline__ float fdot2f(h2v a, h2v b, float c){
#if __has_builtin(__builtin_amdgcn_fdot2)
    return __builtin_amdgcn_fdot2(a, b, c, false);
#else
    return c + (float)a[0]*(float)b[0] + (float)a[1]*(float)b[1];
#endif
}

// ---------------- CSR build ----------------

__global__ void zero_int(int* __restrict__ p, int n){
    int i = blockIdx.x*256 + threadIdx.x;
    if (i < n) p[i] = 0;
}

__global__ void hist_k(const int* __restrict__ dst, int E, int* __restrict__ cnt){
    int e = blockIdx.x*256 + threadIdx.x;
    if (e < E) atomicAdd(&cnt[dst[e]], 1);
}

__global__ void scan1_k(const int* __restrict__ deg, int Nn, int* __restrict__ rp, int* __restrict__ bsum){
    __shared__ int s[256];
    int t = threadIdx.x, b = blockIdx.x;
    int i = b*256 + t;
    int v = (i < Nn) ? deg[i] : 0;
    s[t] = v;
    __syncthreads();
    #pragma unroll
    for (int d = 1; d < 256; d <<= 1){
        int u = (t >= d) ? s[t-d] : 0;
        __syncthreads();
        s[t] += u;
        __syncthreads();
    }
    if (i < Nn) rp[i] = s[t] - v;
    if (t == 255) bsum[b] = s[255];
}

__global__ void scan2_k(const int* __restrict__ bsum, int nb, int* __restrict__ bsumx){
    __shared__ int s[256];
    int t = threadIdx.x;
    int v = (t < nb) ? bsum[t] : 0;
    s[t] = v;
    __syncthreads();
    #pragma unroll
    for (int d = 1; d < 256; d <<= 1){
        int u = (t >= d) ? s[t-d] : 0;
        __syncthreads();
        s[t] += u;
        __syncthreads();
    }
    if (t < nb) bsumx[t] = s[t] - v;
}

// finalize rp, init cursor, and place self-loop item
__global__ void scan3_k(int* __restrict__ rp, const int* __restrict__ bsumx,
                        int* __restrict__ cnt, int* __restrict__ items, int Nn, int E){
    int b = blockIdx.x, t = threadIdx.x;
    int i = b*256 + t;
    if (i < Nn){
        int r = rp[i] + bsumx[b];
        rp[i]  = r;
        cnt[i] = r;
        items[r + i] = i;          // self-loop slot
    }
    if (b == 0 && t == 0) rp[Nn] = E;
}

__global__ void scatter_k(const int* __restrict__ src, const int* __restrict__ dst,
                          int E, int* __restrict__ cnt, int* __restrict__ items){
    int e = blockIdx.x*256 + threadIdx.x;
    if (e < E){
        int d = dst[e];
        int pos = atomicAdd(&cnt[d], 1);
        items[pos + d + 1] = src[e];
    }
}

// ---------------- fused conversions ----------------
// seg0: x (N*64 float4 groups) -> xA fp16
// seg1: W1 pair -> bt1 [512][256] fp16 transposed
// seg2: W2 pair -> bt2 [128][256]
// seg3: att1 (256) + att2 (64)
__global__ void cvt_all_k(const float* __restrict__ x,
                          const float* __restrict__ Wl1, const float* __restrict__ Wr1,
                          const float* __restrict__ Wl2, const float* __restrict__ Wr2,
                          const float* __restrict__ att1, const float* __restrict__ att2,
                          _Float16* __restrict__ xA, _Float16* __restrict__ bt1,
                          _Float16* __restrict__ bt2,
                          _Float16* __restrict__ a1h, _Float16* __restrict__ a2h,
                          int n4)
{
    int t = blockIdx.x*256 + threadIdx.x;
    if (t < n4){
        float4 v = reinterpret_cast<const float4*>(x)[t];
        U2 o;
        o.h[0][0] = (_Float16)v.x; o.h[0][1] = (_Float16)v.y;
        o.h[1][0] = (_Float16)v.z; o.h[1][1] = (_Float16)v.w;
        reinterpret_cast<uint2*>(xA)[t] = o.u;
        return;
    }
    int u = t - n4;
    if (u < 512*256){
        int k = u & 255, nn = u >> 8;
        float v = (nn < 256) ? Wl1[(size_t)k*256 + nn] : Wr1[(size_t)k*256 + (nn-256)];
        bt1[u] = (_Float16)v;
        return;
    }
    u -= 512*256;
    if (u < 128*256){
        int k = u & 255, nn = u >> 8;
        float v = (nn < 64) ? Wl2[(size_t)k*64 + nn] : Wr2[(size_t)k*64 + (nn-64)];
        bt2[u] = (_Float16)v;
        return;
    }
    u -= 128*256;
    if (u < 256){ a1h[u] = (_Float16)att1[u]; return; }
    u -= 256;
    if (u < 64){ a2h[u] = (_Float16)att2[u]; }
}

// ---------------- fp16 MFMA GEMM: C = A @ B, B given as Bt[Ntot][K], all fp16 ----------------
__global__ __launch_bounds__(256) void gemm_f16(
    const _Float16* __restrict__ A, const _Float16* __restrict__ Bt,
    _Float16* __restrict__ C, int M, int Ntot, int K)
{
    __shared__ __align__(16) _Float16 sA[128*40];
    __shared__ __align__(16) _Float16 sB[128*40];

    int t = threadIdx.x;
    int lane = t & 63, wave = t >> 6;
    int wm = (wave >> 1) * 64, wn = (wave & 1) * 64;
    int m0 = blockIdx.y * 128, n0 = blockIdx.x * 128;
    int lm = lane & 15, kq = lane >> 4;

    f32x4 acc[4][4] = {};

    for (int kc = 0; kc < K; kc += 32){
        __syncthreads();
        #pragma unroll
        for (int it = 0; it < 2; ++it){
            int idx = t + 256*it;
            int r = idx >> 2, s = (idx & 3) * 8;
            uint4 va = make_uint4(0u,0u,0u,0u);
            if (m0 + r < M)
                va = *reinterpret_cast<const uint4*>(A + (size_t)(m0 + r)*K + kc + s);
            *reinterpret_cast<uint4*>(sA + r*40 + s) = va;
            *reinterpret_cast<uint4*>(sB + r*40 + s) =
                *reinterpret_cast<const uint4*>(Bt + (size_t)(n0 + r)*K + kc + s);
        }
        __syncthreads();

        f16x8 fa[4], fb[4];
        #pragma unroll
        for (int i = 0; i < 4; ++i){
            fa[i] = *reinterpret_cast<const f16x8*>(sA + (wm + i*16 + lm)*40 + kq*8);
            fb[i] = *reinterpret_cast<const f16x8*>(sB + (wn + i*16 + lm)*40 + kq*8);
        }
        #pragma unroll
        for (int i = 0; i < 4; ++i)
            #pragma unroll
            for (int j = 0; j < 4; ++j)
                acc[i][j] = __builtin_amdgcn_mfma_f32_16x16x32_f16(fa[i], fb[j], acc[i][j], 0, 0, 0);
    }

    #pragma unroll
    for (int i = 0; i < 4; ++i){
        #pragma unroll
        for (int r = 0; r < 4; ++r){
            int m = m0 + wm + i*16 + kq*4 + r;
            if (m < M){
                #pragma unroll
                for (int j = 0; j < 4; ++j)
                    C[(size_t)m*Ntot + n0 + wn + j*16 + lm] = (_Float16)acc[i][j][r];
            }
        }
    }
}

// ---------------- layer-1 aggregation: quarter = item, lane = 16 channels ----------------
// xlr [N][512] fp16 (xl|xr). Head h = channel>>6; lane r holds ch r*16..r*16+15 (one head).
// Head-score reduce = shfl_xor 1,2 (4-lane groups). ILP-2: items j+q and j+4+q per quarter.
__global__ __launch_bounds__(256) void agg1_k(
    const _Float16* __restrict__ xlr,
    const int* __restrict__ rp, const int* __restrict__ items,
    const _Float16* __restrict__ attH, const float* __restrict__ bias,
    _Float16* __restrict__ h1, int Nn)
{
    int wave = threadIdx.x >> 6, lane = threadIdx.x & 63;
    int i = blockIdx.x*4 + wave;
    if (i >= Nn) return;
    int q = lane >> 4, r = lane & 15;

    const uint4* x4 = reinterpret_cast<const uint4*>(xlr);   // row = 64 uint4
    uint ib = (uint)i * 64u;
    U8 xra, xrb, ata, atb;
    xra.u = x4[ib + 32u + (uint)r*2u];
    xrb.u = x4[ib + 32u + (uint)r*2u + 1u];
    const uint4* a4 = reinterpret_cast<const uint4*>(attH);
    ata.u = a4[r*2]; atb.u = a4[r*2+1];

    int beg = rp[i] + i;
    int n   = rp[i+1] + 1 - rp[i];

    float acc[16];
    #pragma unroll
    for (int k = 0; k < 16; ++k) acc[k] = 0.f;
    float l = 0.f;

    auto idxld = [&](int j)->uint {
        int jj = (j < n) ? j : (n-1);
        return (uint)items[beg + jj] * 64u;
    };

    uint sA = idxld(q), sB = idxld(q+4);
    U8 a0, a1, b0, b1;
    a0.u = x4[sA + (uint)r*2u]; a1.u = x4[sA + (uint)r*2u + 1u];
    b0.u = x4[sB + (uint)r*2u]; b1.u = x4[sB + (uint)r*2u + 1u];

    for (int j = 0; j < n; j += 8){
        uint sA2 = idxld(j+8+q), sB2 = idxld(j+12+q);
        U8 p0, p1, p2, p3;
        p0.u = x4[sA2 + (uint)r*2u]; p1.u = x4[sA2 + (uint)r*2u + 1u];
        p2.u = x4[sB2 + (uint)r*2u]; p3.u = x4[sB2 + (uint)r*2u + 1u];

        U8 tA0, tA1, tB0, tB1;
        tA0.v = lrelu8(a0.v + xra.v);
        tA1.v = lrelu8(a1.v + xrb.v);
        tB0.v = lrelu8(b0.v + xra.v);
        tB1.v = lrelu8(b1.v + xrb.v);
        float pA = 0.f, pB = 0.f;
        #pragma unroll
        for (int k = 0; k < 4; ++k){
            pA = fdot2f(tA0.h[k], ata.h[k], pA);
            pB = fdot2f(tB0.h[k], ata.h[k], pB);
        }
        #pragma unroll
        for (int k = 0; k < 4; ++k){
            pA = fdot2f(tA1.h[k], atb.h[k], pA);
            pB = fdot2f(tB1.h[k], atb.h[k], pB);
        }
        pA += __shfl_xor(pA, 1, 64);  pB += __shfl_xor(pB, 1, 64);
        pA += __shfl_xor(pA, 2, 64);  pB += __shfl_xor(pB, 2, 64);
        float wA = (j+q   < n) ? __expf(pA) : 0.f;
        float wB = (j+4+q < n) ? __expf(pB) : 0.f;
        l += wA + wB;
        #pragma unroll
        for (int k = 0; k < 8; ++k){
            acc[k]   = fmaf((float)a0.v[k], wA, acc[k]);
            acc[k+8] = fmaf((float)a1.v[k], wA, acc[k+8]);
        }
        #pragma unroll
        for (int k = 0; k < 8; ++k){
            acc[k]   = fmaf((float)b0.v[k], wB, acc[k]);
            acc[k+8] = fmaf((float)b1.v[k], wB, acc[k+8]);
        }
        a0 = p0; a1 = p1; b0 = p2; b1 = p3;
    }

    // merge the 4 quarters
    #pragma unroll
    for (int k = 0; k < 16; ++k){
        acc[k] += __shfl_xor(acc[k], 16, 64);
        acc[k] += __shfl_xor(acc[k], 32, 64);
    }
    l += __shfl_xor(l, 16, 64);
    l += __shfl_xor(l, 32, 64);

    if (q == 0){
        float inv = 1.f / l;
        U8 o0, o1;
        #pragma unroll
        for (int k = 0; k < 8; ++k){
            o0.v[k] = (_Float16)fmaxf(acc[k]  *inv + bias[r*16 + k],     0.f);
            o1.v[k] = (_Float16)fmaxf(acc[k+8]*inv + bias[r*16 + 8 + k], 0.f);
        }
        uint4* h4 = reinterpret_cast<uint4*>(h1);           // row = 32 uint4
        h4[(uint)i*32u + (uint)r*2u]      = o0.u;
        h4[(uint)i*32u + (uint)r*2u + 1u] = o1.u;
    }
}

// ---------------- layer-2 fused aggregation + final linear: quarter = item, lane = 4 ch ----------------
// xlr [N][128] fp16 (xl|xr). Score reduce over 16 lanes (4 stages). ILP-2 per quarter.
__global__ __launch_bounds__(256) void agg2_k(
    const _Float16* __restrict__ xlr,
    const int* __restrict__ rp, const int* __restrict__ items,
    const _Float16* __restrict__ attH, const float* __restrict__ bias,
    const float* __restrict__ Wlin, const float* __restrict__ blin,
    float* __restrict__ out, int Nn)
{
    int wave = threadIdx.x >> 6, lane = threadIdx.x & 63;
    int i = blockIdx.x*4 + wave;
    if (i >= Nn) return;
    int q = lane >> 4, r = lane & 15;

    const uint2* x2 = reinterpret_cast<const uint2*>(xlr);   // row = 32 uint2
    uint ib = (uint)i * 32u;
    U2 xr; xr.u = x2[ib + 16u + (uint)r];
    U2 at; at.u = reinterpret_cast<const uint2*>(attH)[r];

    int beg = rp[i] + i;
    int n   = rp[i+1] + 1 - rp[i];

    auto idxld = [&](int j)->uint {
        int jj = (j < n) ? j : (n-1);
        return (uint)items[beg + jj] * 32u;
    };

    float l = 0.f;
    float4 acc = make_float4(0.f,0.f,0.f,0.f);

    uint sA = idxld(q), sB = idxld(q+4);
    U2 a, b;
    a.u = x2[sA + (uint)r];
    b.u = x2[sB + (uint)r];

    for (int j = 0; j < n; j += 8){
        uint sA2 = idxld(j+8+q), sB2 = idxld(j+12+q);
        U2 pa, pb;
        pa.u = x2[sA2 + (uint)r];
        pb.u = x2[sB2 + (uint)r];

        h2v tA0 = lrelu2(a.h[0] + xr.h[0]);
        h2v tA1 = lrelu2(a.h[1] + xr.h[1]);
        h2v tB0 = lrelu2(b.h[0] + xr.h[0]);
        h2v tB1 = lrelu2(b.h[1] + xr.h[1]);
        float pA = fdot2f(tA1, at.h[1], fdot2f(tA0, at.h[0], 0.f));
        float pB = fdot2f(tB1, at.h[1], fdot2f(tB0, at.h[0], 0.f));
        pA += __shfl_xor(pA, 1, 64);  pB += __shfl_xor(pB, 1, 64);
        pA += __shfl_xor(pA, 2, 64);  pB += __shfl_xor(pB, 2, 64);
        pA += __shfl_xor(pA, 4, 64);  pB += __shfl_xor(pB, 4, 64);
        pA += __shfl_xor(pA, 8, 64);  pB += __shfl_xor(pB, 8, 64);
        float wA = (j+q   < n) ? __expf(pA) : 0.f;
        float wB = (j+4+q < n) ? __expf(pB) : 0.f;
        l += wA + wB;
        acc.x = fmaf((float)a.h[0][0], wA, acc.x);
        acc.y = fmaf((float)a.h[0][1], wA, acc.y);
        acc.z = fmaf((float)a.h[1][0], wA, acc.z);
        acc.w = fmaf((float)a.h[1][1], wA, acc.w);
        acc.x = fmaf((float)b.h[0][0], wB, acc.x);
        acc.y = fmaf((float)b.h[0][1], wB, acc.y);
        acc.z = fmaf((float)b.h[1][0], wB, acc.z);
        acc.w = fmaf((float)b.h[1][1], wB, acc.w);
        a = pa; b = pb;
    }

    // merge the 4 quarters
    #pragma unroll
    for (int s = 16; s <= 32; s <<= 1){
        l     += __shfl_xor(l, s, 64);
        acc.x += __shfl_xor(acc.x, s, 64);
        acc.y += __shfl_xor(acc.y, s, 64);
        acc.z += __shfl_xor(acc.z, s, 64);
        acc.w += __shfl_xor(acc.w, s, 64);
    }
    float inv = 1.f / l;
    float4 b4 = reinterpret_cast<const float4*>(bias)[r];
    float4 hc;
    hc.x = fmaxf(acc.x*inv + b4.x, 0.f);
    hc.y = fmaxf(acc.y*inv + b4.y, 0.f);
    hc.z = fmaxf(acc.z*inv + b4.z, 0.f);
    hc.w = fmaxf(acc.w*inv + b4.w, 0.f);
    for (int c = q; c < 10; c += 4){
        float p = hc.x * Wlin[(r*4+0)*10 + c]
                + hc.y * Wlin[(r*4+1)*10 + c]
                + hc.z * Wlin[(r*4+2)*10 + c]
                + hc.w * Wlin[(r*4+3)*10 + c];
        p += __shfl_xor(p, 8, 64);
        p += __shfl_xor(p, 4, 64);
        p += __shfl_xor(p, 2, 64);
        p += __shfl_xor(p, 1, 64);
        if (r == 0) out[(size_t)i*10 + c] = p + blin[c];
    }
}

// ---------------- launch ----------------

extern "C" void kernel_launch(void* const* d_in, const int* in_sizes, int n_in,
                              void* d_out, int out_size, void* d_ws, size_t ws_size,
                              hipStream_t stream)
{
    const float* x    = (const float*)d_in[0];
    const int*   ei   = (const int*)  d_in[1];
    const float* Wl1  = (const float*)d_in[2];
    const float* Wr1  = (const float*)d_in[3];
    const float* att1 = (const float*)d_in[4];
    const float* b1   = (const float*)d_in[5];
    const float* Wl2  = (const float*)d_in[6];
    const float* Wr2  = (const float*)d_in[7];
    const float* att2 = (const float*)d_in[8];
    const float* b2   = (const float*)d_in[9];
    const float* Wlin = (const float*)d_in[10];
    const float* blin = (const float*)d_in[11];
    float* out = (float*)d_out;

    const int N = in_sizes[0] / 256;
    const int E = in_sizes[1] / 2;
    const int K = 256;
    const int* srcp = ei;
    const int* dstp = ei + E;

    char* ws = (char*)d_ws;
    size_t off = 0;
    auto alloc = [&](size_t bytes)->char*{
        char* p = ws + off;
        off += (bytes + 255) & ~(size_t)255;
        return p;
    };
    _Float16* xlr1 = (_Float16*)alloc((size_t)N*512*2);
    _Float16* xlr2 = (_Float16*)alloc((size_t)N*128*2);
    _Float16* xA   = (_Float16*)alloc((size_t)N*256*2);
    _Float16* h1   = (_Float16*)alloc((size_t)N*256*2);
    _Float16* bt1  = (_Float16*)alloc((size_t)512*K*2);
    _Float16* bt2  = (_Float16*)alloc((size_t)128*K*2);
    _Float16* a1h  = (_Float16*)alloc(256*2);
    _Float16* a2h  = (_Float16*)alloc(64*2);
    int* rp    = (int*)alloc((size_t)(N+1)*4);
    int* cnt   = (int*)alloc((size_t)N*4);
    int* bsum  = (int*)alloc(256*4);
    int* bsumx = (int*)alloc(256*4);
    int* items = (int*)alloc((size_t)(E+N)*4);
    (void)ws_size;

    const int nb = (N + 255) / 256;
    const int eb = (E + 255) / 256;

    // CSR build (items = self + edges per node)
    hipLaunchKernelGGL(zero_int,  dim3(nb), dim3(256), 0, stream, cnt, N);
    hipLaunchKernelGGL(hist_k,    dim3(eb), dim3(256), 0, stream, dstp, E, cnt);
    hipLaunchKernelGGL(scan1_k,   dim3(nb), dim3(256), 0, stream, cnt, N, rp, bsum);
    hipLaunchKernelGGL(scan2_k,   dim3(1),  dim3(256), 0, stream, bsum, nb, bsumx);
    hipLaunchKernelGGL(scan3_k,   dim3(nb), dim3(256), 0, stream, rp, bsumx, cnt, items, N, E);
    hipLaunchKernelGGL(scatter_k, dim3(eb), dim3(256), 0, stream, srcp, dstp, E, cnt, items);

    // fused conversions
    const int n4 = N*64;
    const int cvt_total = n4 + 512*256 + 128*256 + 256 + 64;
    hipLaunchKernelGGL(cvt_all_k, dim3((cvt_total + 255)/256), dim3(256), 0, stream,
                       x, Wl1, Wr1, Wl2, Wr2, att1, att2,
                       xA, bt1, bt2, a1h, a2h, n4);

    // layer 1
    hipLaunchKernelGGL(gemm_f16, dim3(4, (N+127)/128), dim3(256), 0, stream,
                       xA, bt1, xlr1, N, 512, K);
    hipLaunchKernelGGL(agg1_k, dim3((N+3)/4), dim3(256), 0, stream,
                       xlr1, rp, items, a1h, b1, h1, N);

    // layer 2
    hipLaunchKernelGGL(gemm_f16, dim3(1, (N+127)/128), dim3(256), 0, stream,
                       h1, bt2, xlr2, N, 128, K);
    hipLaunchKernelGGL(agg2_k, dim3((N+3)/4), dim3(256), 0, stream,
                       xlr2, rp, items, a2h, b2, Wlin, blin, out, N);
}

// Round 10
// 365.759 us; speedup vs baseline: 1.1819x; 1.1018x over previous
//
#include <hip/hip_runtime.h>
#include <hip/hip_fp16.h>
#include <math.h>

#define NEG_SLOPE 0.2f

typedef _Float16 f16x8 __attribute__((ext_vector_type(8)));
typedef float f32x4  __attribute__((ext_vector_type(4)));
typedef _Float16 h2v __attribute__((ext_vector_type(2)));

union U8 { uint4 u; f16x8 v; h2v h[4]; };
union U2 { uint2 u; h2v h[2]; };

__device__ __forceinline__ f16x8 lrelu8(f16x8 s){
    return __builtin_elementwise_max(s, s * (_Float16)NEG_SLOPE);
}
__device__ __forceinline__ h2v lrelu2(h2v s){
    return __builtin_elementwise_max(s, s * (_Float16)NEG_SLOPE);
}
__device__ __forceinline__ float fdot2f(h2v a, h2v b, float c){
#if __has_builtin(__builtin_amdgcn_fdot2)
    return __builtin_amdgcn_fdot2(a, b, c, false);
#else
    return c + (float)a[0]*(float)b[0] + (float)a[1]*(float)b[1];
#endif
}

// ---------------- CSR build ----------------

__global__ void zero_int(int* __restrict__ p, int n){
    int i = blockIdx.x*256 + threadIdx.x;
    if (i < n) p[i] = 0;
}

__global__ void hist_k(const int* __restrict__ dst, int E, int* __restrict__ cnt){
    int e = blockIdx.x*256 + threadIdx.x;
    if (e < E) atomicAdd(&cnt[dst[e]], 1);
}

__global__ void scan1_k(const int* __restrict__ deg, int Nn, int* __restrict__ rp, int* __restrict__ bsum){
    __shared__ int s[256];
    int t = threadIdx.x, b = blockIdx.x;
    int i = b*256 + t;
    int v = (i < Nn) ? deg[i] : 0;
    s[t] = v;
    __syncthreads();
    #pragma unroll
    for (int d = 1; d < 256; d <<= 1){
        int u = (t >= d) ? s[t-d] : 0;
        __syncthreads();
        s[t] += u;
        __syncthreads();
    }
    if (i < Nn) rp[i] = s[t] - v;
    if (t == 255) bsum[b] = s[255];
}

__global__ void scan2_k(const int* __restrict__ bsum, int nb, int* __restrict__ bsumx){
    __shared__ int s[256];
    int t = threadIdx.x;
    int v = (t < nb) ? bsum[t] : 0;
    s[t] = v;
    __syncthreads();
    #pragma unroll
    for (int d = 1; d < 256; d <<= 1){
        int u = (t >= d) ? s[t-d] : 0;
        __syncthreads();
        s[t] += u;
        __syncthreads();
    }
    if (t < nb) bsumx[t] = s[t] - v;
}

// finalize rp, init cursor, place self-loop item
__global__ void scan3_k(int* __restrict__ rp, const int* __restrict__ bsumx,
                        int* __restrict__ cnt, int* __restrict__ items, int Nn, int E){
    int b = blockIdx.x, t = threadIdx.x;
    int i = b*256 + t;
    if (i < Nn){
        int r = rp[i] + bsumx[b];
        rp[i]  = r;
        cnt[i] = r;
        items[r + i] = i;
    }
    if (b == 0 && t == 0) rp[Nn] = E;
}

__global__ void scatter_k(const int* __restrict__ src, const int* __restrict__ dst,
                          int E, int* __restrict__ cnt, int* __restrict__ items){
    int e = blockIdx.x*256 + threadIdx.x;
    if (e < E){
        int d = dst[e];
        int pos = atomicAdd(&cnt[d], 1);
        items[pos + d + 1] = src[e];
    }
}

// ---------------- fused conversions ----------------
__global__ void cvt_all_k(const float* __restrict__ x,
                          const float* __restrict__ Wl1, const float* __restrict__ Wr1,
                          const float* __restrict__ Wl2, const float* __restrict__ Wr2,
                          const float* __restrict__ att1, const float* __restrict__ att2,
                          const float* __restrict__ Wlin,
                          _Float16* __restrict__ xA, _Float16* __restrict__ bt1,
                          _Float16* __restrict__ bt2,
                          _Float16* __restrict__ a1h, _Float16* __restrict__ a2h,
                          _Float16* __restrict__ WtH,
                          int n4)
{
    int t = blockIdx.x*256 + threadIdx.x;
    if (t < n4){
        float4 v = reinterpret_cast<const float4*>(x)[t];
        U2 o;
        o.h[0][0] = (_Float16)v.x; o.h[0][1] = (_Float16)v.y;
        o.h[1][0] = (_Float16)v.z; o.h[1][1] = (_Float16)v.w;
        reinterpret_cast<uint2*>(xA)[t] = o.u;
        return;
    }
    int u = t - n4;
    if (u < 512*256){
        int k = u & 255, nn = u >> 8;
        float v = (nn < 256) ? Wl1[(size_t)k*256 + nn] : Wr1[(size_t)k*256 + (nn-256)];
        bt1[u] = (_Float16)v;
        return;
    }
    u -= 512*256;
    if (u < 128*256){
        int k = u & 255, nn = u >> 8;
        float v = (nn < 64) ? Wl2[(size_t)k*64 + nn] : Wr2[(size_t)k*64 + (nn-64)];
        bt2[u] = (_Float16)v;
        return;
    }
    u -= 128*256;
    if (u < 256){ a1h[u] = (_Float16)att1[u]; return; }
    u -= 256;
    if (u < 64){ a2h[u] = (_Float16)att2[u]; return; }
    u -= 64;
    if (u < 640){                       // WtH[10][64] = Wlin^T
        int c = u >> 6, ch = u & 63;
        WtH[u] = (_Float16)Wlin[ch*10 + c];
    }
}

// ---------------- fp16 MFMA GEMM: C = A @ B, B given as Bt[Ntot][K] ----------------
__global__ __launch_bounds__(256) void gemm_f16(
    const _Float16* __restrict__ A, const _Float16* __restrict__ Bt,
    _Float16* __restrict__ C, int M, int Ntot, int K)
{
    __shared__ __align__(16) _Float16 sA[128*40];
    __shared__ __align__(16) _Float16 sB[128*40];

    int t = threadIdx.x;
    int lane = t & 63, wave = t >> 6;
    int wm = (wave >> 1) * 64, wn = (wave & 1) * 64;
    int m0 = blockIdx.y * 128, n0 = blockIdx.x * 128;
    int lm = lane & 15, kq = lane >> 4;

    f32x4 acc[4][4] = {};

    for (int kc = 0; kc < K; kc += 32){
        __syncthreads();
        #pragma unroll
        for (int it = 0; it < 2; ++it){
            int idx = t + 256*it;
            int r = idx >> 2, s = (idx & 3) * 8;
            uint4 va = make_uint4(0u,0u,0u,0u);
            if (m0 + r < M)
                va = *reinterpret_cast<const uint4*>(A + (size_t)(m0 + r)*K + kc + s);
            *reinterpret_cast<uint4*>(sA + r*40 + s) = va;
            *reinterpret_cast<uint4*>(sB + r*40 + s) =
                *reinterpret_cast<const uint4*>(Bt + (size_t)(n0 + r)*K + kc + s);
        }
        __syncthreads();

        f16x8 fa[4], fb[4];
        #pragma unroll
        for (int i = 0; i < 4; ++i){
            fa[i] = *reinterpret_cast<const f16x8*>(sA + (wm + i*16 + lm)*40 + kq*8);
            fb[i] = *reinterpret_cast<const f16x8*>(sB + (wn + i*16 + lm)*40 + kq*8);
        }
        #pragma unroll
        for (int i = 0; i < 4; ++i)
            #pragma unroll
            for (int j = 0; j < 4; ++j)
                acc[i][j] = __builtin_amdgcn_mfma_f32_16x16x32_f16(fa[i], fb[j], acc[i][j], 0, 0, 0);
    }

    #pragma unroll
    for (int i = 0; i < 4; ++i){
        #pragma unroll
        for (int r = 0; r < 4; ++r){
            int m = m0 + wm + i*16 + kq*4 + r;
            if (m < M){
                #pragma unroll
                for (int j = 0; j < 4; ++j)
                    C[(size_t)m*Ntot + n0 + wn + j*16 + lm] = (_Float16)acc[i][j][r];
            }
        }
    }
}

// ---------------- layer-1 aggregation (round-8 proven version) ----------------
// quarter = item, lane = 16 channels; ILP-2; head-score reduce shfl_xor 1,2.
__global__ __launch_bounds__(256) void agg1_k(
    const _Float16* __restrict__ xlr,
    const int* __restrict__ rp, const int* __restrict__ items,
    const _Float16* __restrict__ attH, const float* __restrict__ bias,
    _Float16* __restrict__ h1, int Nn)
{
    int wave = threadIdx.x >> 6, lane = threadIdx.x & 63;
    int i = blockIdx.x*4 + wave;
    if (i >= Nn) return;
    int q = lane >> 4, r = lane & 15;

    const uint4* x4 = reinterpret_cast<const uint4*>(xlr);   // row = 64 uint4
    uint ib = (uint)i * 64u;
    U8 xra, xrb, ata, atb;
    xra.u = x4[ib + 32u + (uint)r*2u];
    xrb.u = x4[ib + 32u + (uint)r*2u + 1u];
    const uint4* a4 = reinterpret_cast<const uint4*>(attH);
    ata.u = a4[r*2]; atb.u = a4[r*2+1];

    int beg = rp[i] + i;
    int n   = rp[i+1] + 1 - rp[i];

    float acc[16];
    #pragma unroll
    for (int k = 0; k < 16; ++k) acc[k] = 0.f;
    float l = 0.f;

    auto idxld = [&](int j)->uint {
        int jj = (j < n) ? j : (n-1);
        return (uint)items[beg + jj] * 64u;
    };

    uint sA = idxld(q), sB = idxld(q+4);
    U8 a0, a1, b0, b1;
    a0.u = x4[sA + (uint)r*2u]; a1.u = x4[sA + (uint)r*2u + 1u];
    b0.u = x4[sB + (uint)r*2u]; b1.u = x4[sB + (uint)r*2u + 1u];

    for (int j = 0; j < n; j += 8){
        uint sA2 = idxld(j+8+q), sB2 = idxld(j+12+q);
        U8 p0, p1, p2, p3;
        p0.u = x4[sA2 + (uint)r*2u]; p1.u = x4[sA2 + (uint)r*2u + 1u];
        p2.u = x4[sB2 + (uint)r*2u]; p3.u = x4[sB2 + (uint)r*2u + 1u];

        U8 tA0, tA1, tB0, tB1;
        tA0.v = lrelu8(a0.v + xra.v);
        tA1.v = lrelu8(a1.v + xrb.v);
        tB0.v = lrelu8(b0.v + xra.v);
        tB1.v = lrelu8(b1.v + xrb.v);
        float pA = 0.f, pB = 0.f;
        #pragma unroll
        for (int k = 0; k < 4; ++k){
            pA = fdot2f(tA0.h[k], ata.h[k], pA);
            pB = fdot2f(tB0.h[k], ata.h[k], pB);
        }
        #pragma unroll
        for (int k = 0; k < 4; ++k){
            pA = fdot2f(tA1.h[k], atb.h[k], pA);
            pB = fdot2f(tB1.h[k], atb.h[k], pB);
        }
        pA += __shfl_xor(pA, 1, 64);  pB += __shfl_xor(pB, 1, 64);
        pA += __shfl_xor(pA, 2, 64);  pB += __shfl_xor(pB, 2, 64);
        float wA = (j+q   < n) ? __expf(pA) : 0.f;
        float wB = (j+4+q < n) ? __expf(pB) : 0.f;
        l += wA + wB;
        #pragma unroll
        for (int k = 0; k < 8; ++k){
            acc[k]   = fmaf((float)a0.v[k], wA, acc[k]);
            acc[k+8] = fmaf((float)a1.v[k], wA, acc[k+8]);
        }
        #pragma unroll
        for (int k = 0; k < 8; ++k){
            acc[k]   = fmaf((float)b0.v[k], wB, acc[k]);
            acc[k+8] = fmaf((float)b1.v[k], wB, acc[k+8]);
        }
        a0 = p0; a1 = p1; b0 = p2; b1 = p3;
    }

    // merge the 4 quarters
    #pragma unroll
    for (int k = 0; k < 16; ++k){
        acc[k] += __shfl_xor(acc[k], 16, 64);
        acc[k] += __shfl_xor(acc[k], 32, 64);
    }
    l += __shfl_xor(l, 16, 64);
    l += __shfl_xor(l, 32, 64);

    if (q == 0){
        float inv = 1.f / l;
        U8 o0, o1;
        #pragma unroll
        for (int k = 0; k < 8; ++k){
            o0.v[k] = (_Float16)fmaxf(acc[k]  *inv + bias[r*16 + k],     0.f);
            o1.v[k] = (_Float16)fmaxf(acc[k+8]*inv + bias[r*16 + 8 + k], 0.f);
        }
        uint4* h4 = reinterpret_cast<uint4*>(h1);           // row = 32 uint4
        h4[(uint)i*32u + (uint)r*2u]      = o0.u;
        h4[(uint)i*32u + (uint)r*2u + 1u] = o1.u;
    }
}

// ---------------- layer-2 aggregation: 8-lane group = node, lane = 8 ch ----------------
// 8 nodes per wave; per-group loop over its OWN n (shuffle partners share n, no
// cross-group coupling). Ring-3 row prefetch, index fetched 1 iter ahead, all clamped.
// Writes relu'd h2 fp16 [N][64]; final linear in lin_k.
__global__ __launch_bounds__(256) void agg2_k(
    const _Float16* __restrict__ xlr,
    const int* __restrict__ rp, const int* __restrict__ items,
    const _Float16* __restrict__ attH, const float* __restrict__ bias,
    _Float16* __restrict__ h2, int Nn)
{
    int wave = threadIdx.x >> 6, lane = threadIdx.x & 63;
    int g = lane >> 3, r = lane & 7;
    int i0 = blockIdx.x*32 + wave*8 + g;
    bool ok = (i0 < Nn);
    int i = ok ? i0 : (Nn-1);

    const uint4* x4 = reinterpret_cast<const uint4*>(xlr);   // row = 16 uint4
    U8 xr, at;
    xr.u = x4[(uint)i*16u + 8u + (uint)r];
    at.u = reinterpret_cast<const uint4*>(attH)[r];

    int beg = rp[i] + i;
    int n   = rp[i+1] + 1 - rp[i];        // >= 1; uniform within the 8-lane group

    auto idxOf = [&](int j)->uint {
        int jj = (j < n) ? j : (n-1);
        return (uint)items[beg + jj] * 16u;
    };

    float acc[8];
    #pragma unroll
    for (int k = 0; k < 8; ++k) acc[k] = 0.f;
    float l = 0.f;

    uint s3 = idxOf(3);
    U8 v0, v1, v2;
    v0.u = x4[idxOf(0) + (uint)r];
    v1.u = x4[idxOf(1) + (uint)r];
    v2.u = x4[idxOf(2) + (uint)r];

    for (int j = 0; j < n; ++j){
        uint s4 = idxOf(j+4);
        U8 pv; pv.u = x4[s3 + (uint)r];

        U8 t; t.v = lrelu8(v0.v + xr.v);
        float p = 0.f;
        #pragma unroll
        for (int k = 0; k < 4; ++k) p = fdot2f(t.h[k], at.h[k], p);
        p += __shfl_xor(p, 1, 64);
        p += __shfl_xor(p, 2, 64);
        p += __shfl_xor(p, 4, 64);
        float w = __expf(p);
        l += w;
        #pragma unroll
        for (int k = 0; k < 8; ++k) acc[k] += w * (float)v0.v[k];
        v0 = v1; v1 = v2; v2 = pv; s3 = s4;
    }

    if (ok){
        float inv = 1.f / l;
        U8 o;
        #pragma unroll
        for (int k = 0; k < 8; ++k)
            o.v[k] = (_Float16)fmaxf(acc[k]*inv + bias[r*8 + k], 0.f);
        reinterpret_cast<uint4*>(h2)[(uint)i0*8u + (uint)r] = o.u;
    }
}

// ---------------- final linear: thread per (node, class) ----------------
__global__ __launch_bounds__(256) void lin_k(
    const _Float16* __restrict__ h2, const _Float16* __restrict__ WtH,
    const float* __restrict__ blin, float* __restrict__ out, int Nn)
{
    int t = blockIdx.x*256 + threadIdx.x;
    if (t >= Nn*10) return;
    int i = t / 10, c = t - i*10;
    const uint4* hrow = reinterpret_cast<const uint4*>(h2 + (size_t)i*64);
    const uint4* wrow = reinterpret_cast<const uint4*>(WtH + c*64);
    float p = 0.f;
    #pragma unroll
    for (int b = 0; b < 8; ++b){
        U8 h, w;
        h.u = hrow[b]; w.u = wrow[b];
        #pragma unroll
        for (int k = 0; k < 4; ++k) p = fdot2f(h.h[k], w.h[k], p);
    }
    out[t] = p + blin[c];
}

// ---------------- launch ----------------

extern "C" void kernel_launch(void* const* d_in, const int* in_sizes, int n_in,
                              void* d_out, int out_size, void* d_ws, size_t ws_size,
                              hipStream_t stream)
{
    const float* x    = (const float*)d_in[0];
    const int*   ei   = (const int*)  d_in[1];
    const float* Wl1  = (const float*)d_in[2];
    const float* Wr1  = (const float*)d_in[3];
    const float* att1 = (const float*)d_in[4];
    const float* b1   = (const float*)d_in[5];
    const float* Wl2  = (const float*)d_in[6];
    const float* Wr2  = (const float*)d_in[7];
    const float* att2 = (const float*)d_in[8];
    const float* b2   = (const float*)d_in[9];
    const float* Wlin = (const float*)d_in[10];
    const float* blin = (const float*)d_in[11];
    float* out = (float*)d_out;

    const int N = in_sizes[0] / 256;
    const int E = in_sizes[1] / 2;
    const int K = 256;
    const int* srcp = ei;
    const int* dstp = ei + E;

    char* ws = (char*)d_ws;
    size_t off = 0;
    auto alloc = [&](size_t bytes)->char*{
        char* p = ws + off;
        off += (bytes + 255) & ~(size_t)255;
        return p;
    };
    _Float16* xlr1 = (_Float16*)alloc((size_t)N*512*2);
    _Float16* xlr2 = (_Float16*)alloc((size_t)N*128*2);
    _Float16* xA   = (_Float16*)alloc((size_t)N*256*2);
    _Float16* h1   = (_Float16*)alloc((size_t)N*256*2);
    _Float16* h2   = (_Float16*)alloc((size_t)N*64*2);
    _Float16* bt1  = (_Float16*)alloc((size_t)512*K*2);
    _Float16* bt2  = (_Float16*)alloc((size_t)128*K*2);
    _Float16* a1h  = (_Float16*)alloc(256*2);
    _Float16* a2h  = (_Float16*)alloc(64*2);
    _Float16* WtH  = (_Float16*)alloc(640*2);
    int* rp    = (int*)alloc((size_t)(N+1)*4);
    int* cnt   = (int*)alloc((size_t)N*4);
    int* bsum  = (int*)alloc(256*4);
    int* bsumx = (int*)alloc(256*4);
    int* items = (int*)alloc((size_t)(E+N)*4);
    (void)ws_size;

    const int nb = (N + 255) / 256;
    const int eb = (E + 255) / 256;

    // CSR build (items = self + edges per node)
    hipLaunchKernelGGL(zero_int,  dim3(nb), dim3(256), 0, stream, cnt, N);
    hipLaunchKernelGGL(hist_k,    dim3(eb), dim3(256), 0, stream, dstp, E, cnt);
    hipLaunchKernelGGL(scan1_k,   dim3(nb), dim3(256), 0, stream, cnt, N, rp, bsum);
    hipLaunchKernelGGL(scan2_k,   dim3(1),  dim3(256), 0, stream, bsum, nb, bsumx);
    hipLaunchKernelGGL(scan3_k,   dim3(nb), dim3(256), 0, stream, rp, bsumx, cnt, items, N, E);
    hipLaunchKernelGGL(scatter_k, dim3(eb), dim3(256), 0, stream, srcp, dstp, E, cnt, items);

    // fused conversions
    const int n4 = N*64;
    const int cvt_total = n4 + 512*256 + 128*256 + 256 + 64 + 640;
    hipLaunchKernelGGL(cvt_all_k, dim3((cvt_total + 255)/256), dim3(256), 0, stream,
                       x, Wl1, Wr1, Wl2, Wr2, att1, att2, Wlin,
                       xA, bt1, bt2, a1h, a2h, WtH, n4);

    // layer 1
    hipLaunchKernelGGL(gemm_f16, dim3(4, (N+127)/128), dim3(256), 0, stream,
                       xA, bt1, xlr1, N, 512, K);
    hipLaunchKernelGGL(agg1_k, dim3((N+3)/4), dim3(256), 0, stream,
                       xlr1, rp, items, a1h, b1, h1, N);

    // layer 2
    hipLaunchKernelGGL(gemm_f16, dim3(1, (N+127)/128), dim3(256), 0, stream,
                       h1, bt2, xlr2, N, 128, K);
    hipLaunchKernelGGL(agg2_k, dim3((N+31)/32), dim3(256), 0, stream,
                       xlr2, rp, items, a2h, b2, h2, N);
    hipLaunchKernelGGL(lin_k, dim3((N*10+255)/256), dim3(256), 0, stream,
                       h2, WtH, blin, out, N);
}

// Round 11
// 364.409 us; speedup vs baseline: 1.1863x; 1.0037x over previous
//
#include <hip/hip_runtime.h>
#include <hip/hip_fp16.h>
#include <math.h>

#define NEG_SLOPE 0.2f

typedef _Float16 f16x8 __attribute__((ext_vector_type(8)));
typedef float f32x4  __attribute__((ext_vector_type(4)));
typedef float f32x2  __attribute__((ext_vector_type(2)));
typedef _Float16 h2v __attribute__((ext_vector_type(2)));

union U8 { uint4 u; f16x8 v; h2v h[4]; };
union U2 { uint2 u; h2v h[2]; };

#if defined(__has_builtin)
#if __has_builtin(__builtin_amdgcn_global_load_lds)
#define HAS_GLL 1
#endif
#endif
#ifndef HAS_GLL
#define HAS_GLL 0
#endif

#if HAS_GLL
typedef __attribute__((address_space(1))) const unsigned int GU;
typedef __attribute__((address_space(3))) unsigned int LU;
#endif

__device__ __forceinline__ f16x8 lrelu8(f16x8 s){
    return __builtin_elementwise_max(s, s * (_Float16)NEG_SLOPE);
}
__device__ __forceinline__ float fdot2f(h2v a, h2v b, float c){
#if __has_builtin(__builtin_amdgcn_fdot2)
    return __builtin_amdgcn_fdot2(a, b, c, false);
#else
    return c + (float)a[0]*(float)b[0] + (float)a[1]*(float)b[1];
#endif
}

// ---------------- CSR build ----------------

__global__ void hist_k(const int* __restrict__ dst, int E, int* __restrict__ cnt){
    int e = blockIdx.x*256 + threadIdx.x;
    if (e < E) atomicAdd(&cnt[dst[e]], 1);
}

__global__ void scan1_k(const int* __restrict__ deg, int Nn, int* __restrict__ rp, int* __restrict__ bsum){
    __shared__ int s[256];
    int t = threadIdx.x, b = blockIdx.x;
    int i = b*256 + t;
    int v = (i < Nn) ? deg[i] : 0;
    s[t] = v;
    __syncthreads();
    #pragma unroll
    for (int d = 1; d < 256; d <<= 1){
        int u = (t >= d) ? s[t-d] : 0;
        __syncthreads();
        s[t] += u;
        __syncthreads();
    }
    if (i < Nn) rp[i] = s[t] - v;
    if (t == 255) bsum[b] = s[255];
}

__global__ void scan2_k(const int* __restrict__ bsum, int nb, int* __restrict__ bsumx){
    __shared__ int s[256];
    int t = threadIdx.x;
    int v = (t < nb) ? bsum[t] : 0;
    s[t] = v;
    __syncthreads();
    #pragma unroll
    for (int d = 1; d < 256; d <<= 1){
        int u = (t >= d) ? s[t-d] : 0;
        __syncthreads();
        s[t] += u;
        __syncthreads();
    }
    if (t < nb) bsumx[t] = s[t] - v;
}

// finalize rp, init cursor, place self-loop item
__global__ void scan3_k(int* __restrict__ rp, const int* __restrict__ bsumx,
                        int* __restrict__ cnt, int* __restrict__ items, int Nn, int E){
    int b = blockIdx.x, t = threadIdx.x;
    int i = b*256 + t;
    if (i < Nn){
        int r = rp[i] + bsumx[b];
        rp[i]  = r;
        cnt[i] = r;
        items[r + i] = i;
    }
    if (b == 0 && t == 0) rp[Nn] = E;
}

__global__ void scatter_k(const int* __restrict__ src, const int* __restrict__ dst,
                          int E, int* __restrict__ cnt, int* __restrict__ items){
    int e = blockIdx.x*256 + threadIdx.x;
    if (e < E){
        int d = dst[e];
        int pos = atomicAdd(&cnt[d], 1);
        items[pos + d + 1] = src[e];
    }
}

// ---------------- fused conversions ----------------
__global__ void cvt_all_k(const float* __restrict__ x,
                          const float* __restrict__ Wl1, const float* __restrict__ Wr1,
                          const float* __restrict__ Wl2, const float* __restrict__ Wr2,
                          const float* __restrict__ att1, const float* __restrict__ att2,
                          const float* __restrict__ Wlin,
                          _Float16* __restrict__ xA, _Float16* __restrict__ bt1,
                          _Float16* __restrict__ bt2,
                          _Float16* __restrict__ a1h, _Float16* __restrict__ a2h,
                          _Float16* __restrict__ WtH,
                          int n4)
{
    int t = blockIdx.x*256 + threadIdx.x;
    if (t < n4){
        float4 v = reinterpret_cast<const float4*>(x)[t];
        U2 o;
        o.h[0][0] = (_Float16)v.x; o.h[0][1] = (_Float16)v.y;
        o.h[1][0] = (_Float16)v.z; o.h[1][1] = (_Float16)v.w;
        reinterpret_cast<uint2*>(xA)[t] = o.u;
        return;
    }
    int u = t - n4;
    if (u < 512*256){
        int k = u & 255, nn = u >> 8;
        float v = (nn < 256) ? Wl1[(size_t)k*256 + nn] : Wr1[(size_t)k*256 + (nn-256)];
        bt1[u] = (_Float16)v;
        return;
    }
    u -= 512*256;
    if (u < 128*256){
        int k = u & 255, nn = u >> 8;
        float v = (nn < 64) ? Wl2[(size_t)k*64 + nn] : Wr2[(size_t)k*64 + (nn-64)];
        bt2[u] = (_Float16)v;
        return;
    }
    u -= 128*256;
    if (u < 256){ a1h[u] = (_Float16)att1[u]; return; }
    u -= 256;
    if (u < 64){ a2h[u] = (_Float16)att2[u]; return; }
    u -= 64;
    if (u < 640){                       // WtH[10][64] = Wlin^T
        int c = u >> 6, ch = u & 63;
        WtH[u] = (_Float16)Wlin[ch*10 + c];
    }
}

// ---------------- fp16 MFMA GEMM: C = A @ B, B given as Bt[Ntot][K] ----------------
// m97-style: unpadded [128][32] LDS, async global->LDS staging (width 16).
__global__ __launch_bounds__(256) void gemm_f16(
    const _Float16* __restrict__ A, const _Float16* __restrict__ Bt,
    _Float16* __restrict__ C, int M, int Ntot, int K)
{
    __shared__ __align__(16) _Float16 sA[128*32];
    __shared__ __align__(16) _Float16 sB[128*32];

    int t = threadIdx.x;
    int lane = t & 63, wave = t >> 6;
    int wm = (wave >> 1) * 64, wn = (wave & 1) * 64;
    int m0 = blockIdx.y * 128, n0 = blockIdx.x * 128;
    int lm = lane & 15, kq = lane >> 4;

    int r0 = t >> 2, s0 = (t & 3) * 8;      // staging slice (it=0); it=1 -> row +64

    f32x4 acc[4][4] = {};

    for (int kc = 0; kc < K; kc += 32){
        __syncthreads();
#if HAS_GLL
        {
            const _Float16* gA0 = A + (size_t)(m0 + r0)*K + kc + s0;
            const _Float16* gA1 = A + (size_t)(m0 + r0 + 64)*K + kc + s0;
            const _Float16* gB0 = Bt + (size_t)(n0 + r0)*K + kc + s0;
            const _Float16* gB1 = Bt + (size_t)(n0 + r0 + 64)*K + kc + s0;
            if (m0 + r0 < M)
                __builtin_amdgcn_global_load_lds((GU*)gA0, (LU*)(sA + t*8), 16, 0, 0);
            if (m0 + r0 + 64 < M)
                __builtin_amdgcn_global_load_lds((GU*)gA1, (LU*)(sA + (t+256)*8), 16, 0, 0);
            __builtin_amdgcn_global_load_lds((GU*)gB0, (LU*)(sB + t*8), 16, 0, 0);
            __builtin_amdgcn_global_load_lds((GU*)gB1, (LU*)(sB + (t+256)*8), 16, 0, 0);
        }
#else
        #pragma unroll
        for (int it = 0; it < 2; ++it){
            int idx = t + 256*it;
            int rr = idx >> 2, ss = (idx & 3) * 8;
            uint4 va = make_uint4(0u,0u,0u,0u);
            if (m0 + rr < M)
                va = *reinterpret_cast<const uint4*>(A + (size_t)(m0 + rr)*K + kc + ss);
            *reinterpret_cast<uint4*>(sA + rr*32 + ss) = va;
            *reinterpret_cast<uint4*>(sB + rr*32 + ss) =
                *reinterpret_cast<const uint4*>(Bt + (size_t)(n0 + rr)*K + kc + ss);
        }
#endif
        __syncthreads();

        f16x8 fa[4], fb[4];
        #pragma unroll
        for (int i = 0; i < 4; ++i){
            fa[i] = *reinterpret_cast<const f16x8*>(sA + (wm + i*16 + lm)*32 + kq*8);
            fb[i] = *reinterpret_cast<const f16x8*>(sB + (wn + i*16 + lm)*32 + kq*8);
        }
        #pragma unroll
        for (int i = 0; i < 4; ++i)
            #pragma unroll
            for (int j = 0; j < 4; ++j)
                acc[i][j] = __builtin_amdgcn_mfma_f32_16x16x32_f16(fa[i], fb[j], acc[i][j], 0, 0, 0);
    }

    #pragma unroll
    for (int i = 0; i < 4; ++i){
        #pragma unroll
        for (int r = 0; r < 4; ++r){
            int m = m0 + wm + i*16 + kq*4 + r;
            if (m < M){
                #pragma unroll
                for (int j = 0; j < 4; ++j)
                    C[(size_t)m*Ntot + n0 + wn + j*16 + lm] = (_Float16)acc[i][j][r];
            }
        }
    }
}

// ---------------- layer-1 aggregation: quarter = item, lane = 16 channels ----------------
// ILP-2; head-score reduce shfl_xor 1,2; packed f32x2 accumulation.
__global__ __launch_bounds__(256) void agg1_k(
    const _Float16* __restrict__ xlr,
    const int* __restrict__ rp, const int* __restrict__ items,
    const _Float16* __restrict__ attH, const float* __restrict__ bias,
    _Float16* __restrict__ h1, int Nn)
{
    int wave = threadIdx.x >> 6, lane = threadIdx.x & 63;
    int i = blockIdx.x*4 + wave;
    if (i >= Nn) return;
    int q = lane >> 4, r = lane & 15;

    const uint4* x4 = reinterpret_cast<const uint4*>(xlr);   // row = 64 uint4
    uint ib = (uint)i * 64u;
    U8 xra, xrb, ata, atb;
    xra.u = x4[ib + 32u + (uint)r*2u];
    xrb.u = x4[ib + 32u + (uint)r*2u + 1u];
    const uint4* a4 = reinterpret_cast<const uint4*>(attH);
    ata.u = a4[r*2]; atb.u = a4[r*2+1];

    int beg = rp[i] + i;
    int n   = rp[i+1] + 1 - rp[i];

    f32x2 acc2[8];
    #pragma unroll
    for (int k = 0; k < 8; ++k) acc2[k] = (f32x2){0.f, 0.f};
    float l = 0.f;

    auto idxld = [&](int j)->uint {
        int jj = (j < n) ? j : (n-1);
        return (uint)items[beg + jj] * 64u;
    };

    uint sA = idxld(q), sB = idxld(q+4);
    U8 a0, a1, b0, b1;
    a0.u = x4[sA + (uint)r*2u]; a1.u = x4[sA + (uint)r*2u + 1u];
    b0.u = x4[sB + (uint)r*2u]; b1.u = x4[sB + (uint)r*2u + 1u];

    for (int j = 0; j < n; j += 8){
        uint sA2 = idxld(j+8+q), sB2 = idxld(j+12+q);
        U8 p0, p1, p2, p3;
        p0.u = x4[sA2 + (uint)r*2u]; p1.u = x4[sA2 + (uint)r*2u + 1u];
        p2.u = x4[sB2 + (uint)r*2u]; p3.u = x4[sB2 + (uint)r*2u + 1u];

        U8 tA0, tA1, tB0, tB1;
        tA0.v = lrelu8(a0.v + xra.v);
        tA1.v = lrelu8(a1.v + xrb.v);
        tB0.v = lrelu8(b0.v + xra.v);
        tB1.v = lrelu8(b1.v + xrb.v);
        float pA = 0.f, pB = 0.f;
        #pragma unroll
        for (int k = 0; k < 4; ++k){
            pA = fdot2f(tA0.h[k], ata.h[k], pA);
            pB = fdot2f(tB0.h[k], ata.h[k], pB);
        }
        #pragma unroll
        for (int k = 0; k < 4; ++k){
            pA = fdot2f(tA1.h[k], atb.h[k], pA);
            pB = fdot2f(tB1.h[k], atb.h[k], pB);
        }
        pA += __shfl_xor(pA, 1, 64);  pB += __shfl_xor(pB, 1, 64);
        pA += __shfl_xor(pA, 2, 64);  pB += __shfl_xor(pB, 2, 64);
        float wA = (j+q   < n) ? __expf(pA) : 0.f;
        float wB = (j+4+q < n) ? __expf(pB) : 0.f;
        l += wA + wB;
        f32x2 wA2 = {wA, wA}, wB2 = {wB, wB};
        #pragma unroll
        for (int k = 0; k < 4; ++k){
            acc2[k]   += wA2 * __builtin_convertvector(a0.h[k], f32x2)
                       + wB2 * __builtin_convertvector(b0.h[k], f32x2);
            acc2[k+4] += wA2 * __builtin_convertvector(a1.h[k], f32x2)
                       + wB2 * __builtin_convertvector(b1.h[k], f32x2);
        }
        a0 = p0; a1 = p1; b0 = p2; b1 = p3;
    }

    // merge the 4 quarters
    #pragma unroll
    for (int k = 0; k < 8; ++k){
        acc2[k][0] += __shfl_xor(acc2[k][0], 16, 64);
        acc2[k][1] += __shfl_xor(acc2[k][1], 16, 64);
        acc2[k][0] += __shfl_xor(acc2[k][0], 32, 64);
        acc2[k][1] += __shfl_xor(acc2[k][1], 32, 64);
    }
    l += __shfl_xor(l, 16, 64);
    l += __shfl_xor(l, 32, 64);

    if (q == 0){
        float inv = 1.f / l;
        U8 o0, o1;
        #pragma unroll
        for (int k = 0; k < 8; ++k){
            o0.v[k] = (_Float16)fmaxf(acc2[k>>1][k&1]*inv + bias[r*16 + k], 0.f);
            o1.v[k] = (_Float16)fmaxf(acc2[4+(k>>1)][k&1]*inv + bias[r*16 + 8 + k], 0.f);
        }
        uint4* h4 = reinterpret_cast<uint4*>(h1);           // row = 32 uint4
        h4[(uint)i*32u + (uint)r*2u]      = o0.u;
        h4[(uint)i*32u + (uint)r*2u + 1u] = o1.u;
    }
}

// ---------------- layer-2 aggregation: 8-lane group = node, lane = 8 ch ----------------
__global__ __launch_bounds__(256) void agg2_k(
    const _Float16* __restrict__ xlr,
    const int* __restrict__ rp, const int* __restrict__ items,
    const _Float16* __restrict__ attH, const float* __restrict__ bias,
    _Float16* __restrict__ h2, int Nn)
{
    int wave = threadIdx.x >> 6, lane = threadIdx.x & 63;
    int g = lane >> 3, r = lane & 7;
    int i0 = blockIdx.x*32 + wave*8 + g;
    bool ok = (i0 < Nn);
    int i = ok ? i0 : (Nn-1);

    const uint4* x4 = reinterpret_cast<const uint4*>(xlr);   // row = 16 uint4
    U8 xr, at;
    xr.u = x4[(uint)i*16u + 8u + (uint)r];
    at.u = reinterpret_cast<const uint4*>(attH)[r];

    int beg = rp[i] + i;
    int n   = rp[i+1] + 1 - rp[i];        // >= 1; uniform within the 8-lane group

    auto idxOf = [&](int j)->uint {
        int jj = (j < n) ? j : (n-1);
        return (uint)items[beg + jj] * 16u;
    };

    float acc[8];
    #pragma unroll
    for (int k = 0; k < 8; ++k) acc[k] = 0.f;
    float l = 0.f;

    uint s3 = idxOf(3);
    U8 v0, v1, v2;
    v0.u = x4[idxOf(0) + (uint)r];
    v1.u = x4[idxOf(1) + (uint)r];
    v2.u = x4[idxOf(2) + (uint)r];

    for (int j = 0; j < n; ++j){
        uint s4 = idxOf(j+4);
        U8 pv; pv.u = x4[s3 + (uint)r];

        U8 t; t.v = lrelu8(v0.v + xr.v);
        float p = 0.f;
        #pragma unroll
        for (int k = 0; k < 4; ++k) p = fdot2f(t.h[k], at.h[k], p);
        p += __shfl_xor(p, 1, 64);
        p += __shfl_xor(p, 2, 64);
        p += __shfl_xor(p, 4, 64);
        float w = __expf(p);
        l += w;
        #pragma unroll
        for (int k = 0; k < 8; ++k) acc[k] += w * (float)v0.v[k];
        v0 = v1; v1 = v2; v2 = pv; s3 = s4;
    }

    if (ok){
        float inv = 1.f / l;
        U8 o;
        #pragma unroll
        for (int k = 0; k < 8; ++k)
            o.v[k] = (_Float16)fmaxf(acc[k]*inv + bias[r*8 + k], 0.f);
        reinterpret_cast<uint4*>(h2)[(uint)i0*8u + (uint)r] = o.u;
    }
}

// ---------------- final linear: thread per (node, class) ----------------
__global__ __launch_bounds__(256) void lin_k(
    const _Float16* __restrict__ h2, const _Float16* __restrict__ WtH,
    const float* __restrict__ blin, float* __restrict__ out, int Nn)
{
    int t = blockIdx.x*256 + threadIdx.x;
    if (t >= Nn*10) return;
    int i = t / 10, c = t - i*10;
    const uint4* hrow = reinterpret_cast<const uint4*>(h2 + (size_t)i*64);
    const uint4* wrow = reinterpret_cast<const uint4*>(WtH + c*64);
    float p = 0.f;
    #pragma unroll
    for (int b = 0; b < 8; ++b){
        U8 h, w;
        h.u = hrow[b]; w.u = wrow[b];
        #pragma unroll
        for (int k = 0; k < 4; ++k) p = fdot2f(h.h[k], w.h[k], p);
    }
    out[t] = p + blin[c];
}

// ---------------- launch ----------------

extern "C" void kernel_launch(void* const* d_in, const int* in_sizes, int n_in,
                              void* d_out, int out_size, void* d_ws, size_t ws_size,
                              hipStream_t stream)
{
    const float* x    = (const float*)d_in[0];
    const int*   ei   = (const int*)  d_in[1];
    const float* Wl1  = (const float*)d_in[2];
    const float* Wr1  = (const float*)d_in[3];
    const float* att1 = (const float*)d_in[4];
    const float* b1   = (const float*)d_in[5];
    const float* Wl2  = (const float*)d_in[6];
    const float* Wr2  = (const float*)d_in[7];
    const float* att2 = (const float*)d_in[8];
    const float* b2   = (const float*)d_in[9];
    const float* Wlin = (const float*)d_in[10];
    const float* blin = (const float*)d_in[11];
    float* out = (float*)d_out;

    const int N = in_sizes[0] / 256;
    const int E = in_sizes[1] / 2;
    const int K = 256;
    const int* srcp = ei;
    const int* dstp = ei + E;

    char* ws = (char*)d_ws;
    size_t off = 0;
    auto alloc = [&](size_t bytes)->char*{
        char* p = ws + off;
        off += (bytes + 255) & ~(size_t)255;
        return p;
    };
    _Float16* xlr1 = (_Float16*)alloc((size_t)N*512*2);
    _Float16* xlr2 = (_Float16*)alloc((size_t)N*128*2);
    _Float16* xA   = (_Float16*)alloc((size_t)N*256*2);
    _Float16* h1   = (_Float16*)alloc((size_t)N*256*2);
    _Float16* h2   = (_Float16*)alloc((size_t)N*64*2);
    _Float16* bt1  = (_Float16*)alloc((size_t)512*K*2);
    _Float16* bt2  = (_Float16*)alloc((size_t)128*K*2);
    _Float16* a1h  = (_Float16*)alloc(256*2);
    _Float16* a2h  = (_Float16*)alloc(64*2);
    _Float16* WtH  = (_Float16*)alloc(640*2);
    int* rp    = (int*)alloc((size_t)(N+1)*4);
    int* cnt   = (int*)alloc((size_t)N*4);
    int* bsum  = (int*)alloc(256*4);
    int* bsumx = (int*)alloc(256*4);
    int* items = (int*)alloc((size_t)(E+N)*4);
    (void)ws_size;

    const int nb = (N + 255) / 256;
    const int eb = (E + 255) / 256;

    // CSR build (items = self + edges per node)
    hipMemsetAsync(cnt, 0, (size_t)N*4, stream);
    hipLaunchKernelGGL(hist_k,    dim3(eb), dim3(256), 0, stream, dstp, E, cnt);
    hipLaunchKernelGGL(scan1_k,   dim3(nb), dim3(256), 0, stream, cnt, N, rp, bsum);
    hipLaunchKernelGGL(scan2_k,   dim3(1),  dim3(256), 0, stream, bsum, nb, bsumx);
    hipLaunchKernelGGL(scan3_k,   dim3(nb), dim3(256), 0, stream, rp, bsumx, cnt, items, N, E);
    hipLaunchKernelGGL(scatter_k, dim3(eb), dim3(256), 0, stream, srcp, dstp, E, cnt, items);

    // fused conversions
    const int n4 = N*64;
    const int cvt_total = n4 + 512*256 + 128*256 + 256 + 64 + 640;
    hipLaunchKernelGGL(cvt_all_k, dim3((cvt_total + 255)/256), dim3(256), 0, stream,
                       x, Wl1, Wr1, Wl2, Wr2, att1, att2, Wlin,
                       xA, bt1, bt2, a1h, a2h, WtH, n4);

    // layer 1
    hipLaunchKernelGGL(gemm_f16, dim3(4, (N+127)/128), dim3(256), 0, stream,
                       xA, bt1, xlr1, N, 512, K);
    hipLaunchKernelGGL(agg1_k, dim3((N+3)/4), dim3(256), 0, stream,
                       xlr1, rp, items, a1h, b1, h1, N);

    // layer 2
    hipLaunchKernelGGL(gemm_f16, dim3(1, (N+127)/128), dim3(256), 0, stream,
                       h1, bt2, xlr2, N, 128, K);
    hipLaunchKernelGGL(agg2_k, dim3((N+31)/32), dim3(256), 0, stream,
                       xlr2, rp, items, a2h, b2, h2, N);
    hipLaunchKernelGGL(lin_k, dim3((N*10+255)/256), dim3(256), 0, stream,
                       h2, WtH, blin, out, N);
}